// Round 6
// baseline (223.764 us; speedup 1.0000x reference)
//
#include <hip/hip_runtime.h>
#include <hip/hip_bf16.h>
#include <math.h>

#define NND 50000
#define NE 800000
#define NF 128
#define NH 64
#define NB 512
#define KP 30
#define NCLS 10
#define NBKT 196             // fine buckets of 256 dsts
#define BSH 8                // bucket shift (dst >> 8)
#define NTILE 196            // edge tiles of 4096
#define NG1 782              // layer GEMM blocks (64 nodes each)
#define NSET 208             // setup blocks (208*256 = 53248)

typedef __hip_bfloat16 bf16;
typedef unsigned long long u64;
typedef unsigned short ushort_t;
typedef __attribute__((ext_vector_type(8))) short bf16x8;   // 8 bf16 (4 VGPRs)
typedef __attribute__((ext_vector_type(4))) float f32x4;

__device__ __forceinline__ float ldF(const void* p, size_t i, int isbf){
    return isbf ? __bfloat162float(((const bf16*)p)[i]) : ((const float*)p)[i];
}

// fp32 -> bf16 bits, round-to-nearest-even (matches HW/numpy)
__device__ __forceinline__ ushort_t f2bf(float v){
    unsigned u = __float_as_uint(v);
    unsigned r = u + 0x7FFFu + ((u >> 16) & 1u);
    return (ushort_t)(r >> 16);
}

// ---- wave-uniform dtype detection (no LDS, no barriers; all lanes must be active) ----
__device__ __forceinline__ int floatsAreBf16(const unsigned* __restrict__ xw, int tid){
    unsigned w = xw[tid & 63];
    int ex = (int)((w >> 7) & 0xFF);
    u64 m = __ballot(ex >= 100 && ex <= 140);   // low-half bf16 exponent sanity
    return __popcll(m) >= 32;
}
__device__ __forceinline__ int intsAreI64(const int* __restrict__ ew, int tid){
    u64 m = __ballot(ew[2*(tid & 63) + 1] == 0); // LE int64 -> odd words zero
    return __popcll(m) >= 48;
}

// ========== K1: bucket_count(+last-block scan fold) || setup ==========
__global__ __launch_bounds__(256) void k1_kernel(
    const unsigned* __restrict__ xw, const int* __restrict__ ei,
    const int* __restrict__ batch, int* __restrict__ starts,
    const void* W1l, const void* W1r, const void* b1,
    const void* W2l, const void* W2r, const void* b2,
    const void* W3l, const void* W3r, const void* b3,
    const void* convw, const void* convb,
    const void* l1w, const void* l1b, const void* l2w, const void* l2b,
    ushort_t* __restrict__ wB1, ushort_t* __restrict__ wB2, ushort_t* __restrict__ wB3,
    float* __restrict__ b1f, float* __restrict__ b2f, float* __restrict__ b3f,
    float* __restrict__ wT, float* __restrict__ cbf,
    float* __restrict__ l1wf, float* __restrict__ l1bf,
    float* __restrict__ l2wf, float* __restrict__ l2bf,
    int* __restrict__ bcnt, int* __restrict__ dctr,
    int* __restrict__ bbase, int* __restrict__ bcur, int* __restrict__ offs)
{
    int tid = threadIdx.x;
    if (blockIdx.x < NTILE){
        // ---- bucket count ----
        __shared__ int lh[NBKT];
        __shared__ int sc[NBKT];
        __shared__ int lastFlag;
        int i64 = intsAreI64(ei, tid);
        if (tid < NBKT) lh[tid] = 0;
        __syncthreads();
        int t0 = blockIdx.x*4096;
        if (i64){
            // paired int4 loads: dsts of edges e, e+1 (both lo dwords)
            #pragma unroll 4
            for (int k = 0; k < 8; ++k){
                int e = t0 + k*512 + 2*tid;
                if (e < NE){
                    int4 dp = *(const int4*)&ei[2*NE + 2*e];
                    atomicAdd(&lh[dp.x >> BSH], 1);
                    atomicAdd(&lh[dp.z >> BSH], 1);
                }
            }
        } else {
            #pragma unroll 4
            for (int k = 0; k < 16; ++k){
                int e = t0 + k*256 + tid;
                if (e < NE) atomicAdd(&lh[ei[NE + e] >> BSH], 1);
            }
        }
        __syncthreads();
        if (tid < NBKT && lh[tid]) atomicAdd(&bcnt[tid], lh[tid]);
        __syncthreads();
        if (tid == 0){
            __threadfence();
            int old = atomicAdd(dctr, 1);
            lastFlag = (old == NTILE-1) ? 1 : 0;
        }
        __syncthreads();
        if (lastFlag){
            if (tid < NBKT) sc[tid] = atomicAdd(&bcnt[tid], 0);   // atomic read
            __syncthreads();
            if (tid == 0){
                int acc = 0;
                for (int b = 0; b < NBKT; ++b){
                    bbase[b] = acc; bcur[b] = acc; acc += sc[b];
                }
                bbase[NBKT] = acc;
                offs[NND] = NE;
            }
        }
    } else {
        // ---- setup: starts + weight preconvert + MFMA B-frag swizzle ----
        int wbf = floatsAreBf16(xw, tid);
        int i64 = intsAreI64(ei, tid);
        int i = (blockIdx.x - NTILE)*256 + tid;
        if (i < NND){
            int b  = i64 ? batch[2*i] : batch[i];
            int pb = (i == 0) ? -1 : (i64 ? batch[2*(i-1)] : batch[i-1]);
            for (int g = pb+1; g <= b; ++g) starts[g] = i;
            if (i == NND-1) for (int g = b+1; g <= NB; ++g) starts[g] = NND;
        }
        // B-frag swizzle: [c][t][lane][j]; k=c*32+(lane>>4)*8+j, n=t*16+(lane&15)
        {
            int j = i & 7, lane = (i >> 3) & 63, t = (i >> 9) & 7, c = i >> 12;
            int k = c*32 + (lane >> 4)*8 + j;
            int n = t*16 + (lane & 15);
            if (i < 16384){
                float v = (n < 64) ? ldF(W1l, (size_t)k*NH + n, wbf)
                                   : ldF(W1r, (size_t)k*NH + (n-64), wbf);
                wB1[i] = f2bf(v);
            }
            if (i < 8192){
                float v2 = (n < 64) ? ldF(W2l, (size_t)k*NH + n, wbf)
                                    : ldF(W2r, (size_t)k*NH + (n-64), wbf);
                float v3 = (n < 64) ? ldF(W3l, (size_t)k*NH + n, wbf)
                                    : ldF(W3r, (size_t)k*NH + (n-64), wbf);
                wB2[i] = f2bf(v2);
                wB3[i] = f2bf(v3);
            }
        }
        if (i < 64){
            b1f[i] = ldF(b1, i, wbf);
            b2f[i] = ldF(b2, i, wbf);
            b3f[i] = ldF(b3, i, wbf);
            l1bf[i] = ldF(l1b, i, wbf);
        }
        if (i < 10240){
            int o = i / 320, rem = i - o*320, ch = rem/5, h = rem - ch*5;
            wT[ch*160 + h*32 + o] = ldF(convw, i, wbf);   // wT[ch][h][o]
        }
        if (i < 53248) l1wf[i] = ldF(l1w, i, wbf);
        if (i < 640)   l2wf[i] = ldF(l2w, i, wbf);
        if (i < 32)    cbf[i]  = ldF(convb, i, wbf);
        if (i < 10)    l2bf[i] = ldF(l2b, i, wbf);
    }
}

// ========== K2: layer-1 MFMA GEMM || bucket_scatter (independent) ==========
// bedges entry: (dst<<16) | src  (both < 65536) -- halves scatter traffic.
// Scatter uses STATIC-index myd/mys (VGPR-resident, no scratch).
__global__ __launch_bounds__(256) void k2_kernel(
    const void* __restrict__ x, const int* __restrict__ ei,
    const ushort_t* __restrict__ wB1, const float* __restrict__ b1f,
    ushort_t* __restrict__ ybf, float* __restrict__ z,
    int* __restrict__ bcur, unsigned* __restrict__ bedges)
{
    int tid = threadIdx.x;
    if (blockIdx.x < NG1){
        // ---- L1 GEMM: [y|z] = x @ [W1l|W1r] + [0|b1], K=128 ----
        constexpr int K = NF, KC = K/32, RS = K + 8;
        __shared__ ushort_t hA[64*RS];
        int isbf = floatsAreBf16((const unsigned*)x, tid);
        int base = blockIdx.x * 64;
        // vectorized A-staging: 8 elements per iteration per thread
        if (isbf){
            for (int j = tid; j < 64*K/8; j += 256){
                int r = j >> 4, c8 = (j & 15)*8;
                int node = base + r;
                uint4 v = make_uint4(0u,0u,0u,0u);
                if (node < NND)
                    v = *(const uint4*)((const ushort_t*)x + (size_t)node*K + c8);
                *(uint4*)&hA[r*RS + c8] = v;     // bf16 passthrough (f2bf round-trip exact)
            }
        } else {
            for (int j = tid; j < 64*K/8; j += 256){
                int r = j >> 4, c8 = (j & 15)*8;
                int node = base + r;
                uint4 pk = make_uint4(0u,0u,0u,0u);
                if (node < NND){
                    const float4* xp = (const float4*)((const float*)x + (size_t)node*K + c8);
                    float4 a = xp[0], b = xp[1];
                    pk.x = (unsigned)f2bf(a.x) | ((unsigned)f2bf(a.y) << 16);
                    pk.y = (unsigned)f2bf(a.z) | ((unsigned)f2bf(a.w) << 16);
                    pk.z = (unsigned)f2bf(b.x) | ((unsigned)f2bf(b.y) << 16);
                    pk.w = (unsigned)f2bf(b.z) | ((unsigned)f2bf(b.w) << 16);
                }
                *(uint4*)&hA[r*RS + c8] = pk;
            }
        }
        __syncthreads();
        int lane = tid & 63, w = tid >> 6;
        int n16 = lane & 15, quad = lane >> 4;
        f32x4 acc[8];
        #pragma unroll
        for (int t = 0; t < 8; ++t) acc[t] = (f32x4){0.f,0.f,0.f,0.f};
        const bf16x8* bp = (const bf16x8*)wB1;
        #pragma unroll
        for (int c = 0; c < KC; ++c){
            bf16x8 a = *(const bf16x8*)&hA[(w*16 + n16)*RS + c*32 + quad*8];
            #pragma unroll
            for (int t = 0; t < 8; ++t){
                bf16x8 b = bp[(c*8 + t)*64 + lane];
                acc[t] = __builtin_amdgcn_mfma_f32_16x16x32_bf16(a, b, acc[t], 0, 0, 0);
            }
        }
        #pragma unroll
        for (int t = 0; t < 8; ++t){
            int f = (t & 3)*16 + n16;
            float bv = (t >= 4) ? b1f[f] : 0.f;
            #pragma unroll
            for (int r = 0; r < 4; ++r){
                int node = base + w*16 + quad*4 + r;
                if (node < NND){
                    if (t < 4) ybf[(size_t)node*NH + f] = f2bf(acc[t][r]);
                    else       z[(size_t)node*NH + f] = acc[t][r] + bv;
                }
            }
        }
    } else {
        // ---- bucket scatter (static-index local arrays -> registers) ----
        __shared__ int lh[NBKT];
        __shared__ int lcur[NBKT];
        int i64 = intsAreI64(ei, tid);
        if (tid < NBKT) lh[tid] = 0;
        __syncthreads();
        int t0 = (blockIdx.x - NG1)*4096;
        int myd[16], mys[16];
        if (i64){
            #pragma unroll
            for (int k = 0; k < 8; ++k){
                int e = t0 + k*512 + 2*tid;
                int d0 = -1, d1 = -1, s0 = 0, s1 = 0;
                if (e < NE){
                    int4 sp = *(const int4*)&ei[2*e];
                    int4 dp = *(const int4*)&ei[2*NE + 2*e];
                    d0 = dp.x; s0 = sp.x; d1 = dp.z; s1 = sp.z;
                    atomicAdd(&lh[d0 >> BSH], 1);
                    atomicAdd(&lh[d1 >> BSH], 1);
                }
                myd[2*k]   = d0; mys[2*k]   = s0;
                myd[2*k+1] = d1; mys[2*k+1] = s1;
            }
        } else {
            #pragma unroll
            for (int k = 0; k < 16; ++k){
                int e = t0 + k*256 + tid;
                int d = -1, s_ = 0;
                if (e < NE){
                    d = ei[NE + e]; s_ = ei[e];
                    atomicAdd(&lh[d >> BSH], 1);
                }
                myd[k] = d; mys[k] = s_;
            }
        }
        __syncthreads();
        if (tid < NBKT) lcur[tid] = lh[tid] ? atomicAdd(&bcur[tid], lh[tid]) : 0;
        __syncthreads();
        #pragma unroll
        for (int k = 0; k < 16; ++k){
            if (myd[k] >= 0){
                int b = myd[k] >> BSH;
                int p = atomicAdd(&lcur[b], 1);
                bedges[p] = ((unsigned)myd[k] << 16) | (unsigned)mys[k];
            }
        }
    }
}

// ========== K3: per-bucket fine CSR finalize (separate dispatch; 196 blocks) ==========
__global__ __launch_bounds__(256) void csr_finalize(const unsigned* __restrict__ bedges,
                                                    const int* __restrict__ bbase,
                                                    int* __restrict__ offs,
                                                    ushort_t* __restrict__ csr){
    __shared__ int hist[256];
    int b = blockIdx.x;
    int tid = threadIdx.x;
    int dst0 = b << BSH;
    int nd = NND - dst0; if (nd > 256) nd = 256;
    int e0 = bbase[b], e1 = bbase[b+1];
    hist[tid] = 0;
    __syncthreads();
    for (int e = e0 + tid; e < e1; e += 256)
        atomicAdd(&hist[(int)(bedges[e] >> 16) - dst0], 1);
    __syncthreads();
    int own = hist[tid];
    for (int st = 1; st < 256; st <<= 1){
        int v = (tid >= st) ? hist[tid-st] : 0;
        __syncthreads();
        hist[tid] += v;
        __syncthreads();
    }
    int excl = hist[tid] - own;
    if (tid < nd) offs[dst0 + tid] = e0 + excl;
    __syncthreads();
    hist[tid] = excl;
    __syncthreads();
    for (int e = e0 + tid; e < e1; e += 256){
        unsigned ed = bedges[e];
        int p = atomicAdd(&hist[(int)(ed >> 16) - dst0], 1);
        csr[e0 + p] = (ushort_t)(ed & 0xFFFFu);
    }
}

__device__ __forceinline__ void addbf8(uint4 u, float* a){
    a[0] += __uint_as_float(u.x << 16);
    a[1] += __uint_as_float(u.x & 0xFFFF0000u);
    a[2] += __uint_as_float(u.y << 16);
    a[3] += __uint_as_float(u.y & 0xFFFF0000u);
    a[4] += __uint_as_float(u.z << 16);
    a[5] += __uint_as_float(u.z & 0xFFFF0000u);
    a[6] += __uint_as_float(u.w << 16);
    a[7] += __uint_as_float(u.w & 0xFFFF0000u);
}

// ------ FUSED: h = relu(mean_csr(y)+z) -> LDS A-tile -> MFMA [y'|z'] (layers 2,3) ----
// 512 threads: phase A = 8 threads/node, 8-DEEP load batching (8 outstanding uint4
// loads per round -> half the latency rounds of the 4-deep version). Accumulation
// is applied strictly in csr order -> bitwise identical to shallower unrolls.
__global__ __launch_bounds__(512) void gather_mfma(
    const ushort_t* __restrict__ yb, const int* __restrict__ offs,
    const ushort_t* __restrict__ csr, const float* __restrict__ z,
    const ushort_t* __restrict__ wB, const float* __restrict__ bfp,
    ushort_t* __restrict__ ybf_out, float* __restrict__ z_out,
    ushort_t* __restrict__ ykey_out)
{
    constexpr int K = NH;
    constexpr int KC = K/32;
    constexpr int RS = K + 8;
    __shared__ ushort_t hA[64*RS];
    int tid = threadIdx.x;
    int base = blockIdx.x * 64;

    {   // phase A: gather+finalize 64 nodes into hA, 8 threads per node
        int nl = tid >> 3, q = tid & 7;      // q: 8-feature column group
        int node = base + nl;
        float acc[8];
        #pragma unroll
        for (int i = 0; i < 8; ++i) acc[i] = 0.f;
        ushort_t row[8];
        if (node < NND){
            int o0 = offs[node], o1 = offs[node+1];
            int e = o0;
            for (; e + 7 < o1; e += 8){
                int s0 = csr[e],   s1 = csr[e+1], s2 = csr[e+2], s3 = csr[e+3];
                int s4 = csr[e+4], s5 = csr[e+5], s6 = csr[e+6], s7 = csr[e+7];
                uint4 v0 = *(const uint4*)&yb[(size_t)s0*NH + q*8];
                uint4 v1 = *(const uint4*)&yb[(size_t)s1*NH + q*8];
                uint4 v2 = *(const uint4*)&yb[(size_t)s2*NH + q*8];
                uint4 v3 = *(const uint4*)&yb[(size_t)s3*NH + q*8];
                uint4 v4 = *(const uint4*)&yb[(size_t)s4*NH + q*8];
                uint4 v5 = *(const uint4*)&yb[(size_t)s5*NH + q*8];
                uint4 v6 = *(const uint4*)&yb[(size_t)s6*NH + q*8];
                uint4 v7 = *(const uint4*)&yb[(size_t)s7*NH + q*8];
                addbf8(v0, acc); addbf8(v1, acc); addbf8(v2, acc); addbf8(v3, acc);
                addbf8(v4, acc); addbf8(v5, acc); addbf8(v6, acc); addbf8(v7, acc);
            }
            for (; e + 3 < o1; e += 4){
                int s0 = csr[e], s1 = csr[e+1], s2 = csr[e+2], s3 = csr[e+3];
                uint4 v0 = *(const uint4*)&yb[(size_t)s0*NH + q*8];
                uint4 v1 = *(const uint4*)&yb[(size_t)s1*NH + q*8];
                uint4 v2 = *(const uint4*)&yb[(size_t)s2*NH + q*8];
                uint4 v3 = *(const uint4*)&yb[(size_t)s3*NH + q*8];
                addbf8(v0, acc); addbf8(v1, acc); addbf8(v2, acc); addbf8(v3, acc);
            }
            for (; e < o1; ++e){
                uint4 v0 = *(const uint4*)&yb[(size_t)csr[e]*NH + q*8];
                addbf8(v0, acc);
            }
            float dd = (float)(o1 - o0); dd = dd > 1.f ? dd : 1.f;
            float inv = 1.f / dd;
            const float4* zp = (const float4*)&z[(size_t)node*NH + q*8];
            #pragma unroll
            for (int i4 = 0; i4 < 2; ++i4){
                float4 zz = zp[i4];
                float v0 = acc[i4*4+0]*inv + zz.x;
                float v1 = acc[i4*4+1]*inv + zz.y;
                float v2 = acc[i4*4+2]*inv + zz.z;
                float v3 = acc[i4*4+3]*inv + zz.w;
                row[i4*4+0] = f2bf(v0 > 0.f ? v0 : 0.f);
                row[i4*4+1] = f2bf(v1 > 0.f ? v1 : 0.f);
                row[i4*4+2] = f2bf(v2 > 0.f ? v2 : 0.f);
                row[i4*4+3] = f2bf(v3 > 0.f ? v3 : 0.f);
            }
        } else {
            #pragma unroll
            for (int i = 0; i < 8; ++i) row[i] = 0;
        }
        unsigned pk[4];
        #pragma unroll
        for (int i = 0; i < 4; ++i)
            pk[i] = (unsigned)row[2*i] | ((unsigned)row[2*i+1] << 16);
        *(uint4*)&hA[nl*RS + q*8] = make_uint4(pk[0],pk[1],pk[2],pk[3]);
    }
    __syncthreads();

    int lane = tid & 63, w8 = tid >> 6;
    int wrow = w8 & 3;                 // row-group 0..3 (rows wrow*16..+15)
    int thalf = (w8 >> 2) << 2;        // 0: y-half, 4: z-half
    int n16 = lane & 15, quad = lane >> 4;
    f32x4 acc[4];
    #pragma unroll
    for (int t = 0; t < 4; ++t) acc[t] = (f32x4){0.f,0.f,0.f,0.f};
    const bf16x8* bp = (const bf16x8*)wB;
    #pragma unroll
    for (int c = 0; c < KC; ++c){
        bf16x8 a = *(const bf16x8*)&hA[(wrow*16 + n16)*RS + c*32 + quad*8];
        #pragma unroll
        for (int tt = 0; tt < 4; ++tt){
            bf16x8 b = bp[(c*8 + thalf + tt)*64 + lane];
            acc[tt] = __builtin_amdgcn_mfma_f32_16x16x32_bf16(a, b, acc[tt], 0, 0, 0);
        }
    }
    if (thalf == 0){
        #pragma unroll
        for (int tt = 0; tt < 4; ++tt){
            int f = tt*16 + n16;
            #pragma unroll
            for (int r = 0; r < 4; ++r){
                int node = base + wrow*16 + quad*4 + r;
                if (node < NND){
                    ushort_t yv = f2bf(acc[tt][r]);
                    ybf_out[(size_t)node*NH + f] = yv;
                    if (ykey_out != nullptr && tt == 3 && n16 == 15)
                        ykey_out[node] = yv;          // compact y'[:,63] for sort keys
                }
            }
        }
    } else {
        #pragma unroll
        for (int tt = 0; tt < 4; ++tt){
            int f = tt*16 + n16;
            float bv = bfp[f];
            #pragma unroll
            for (int r = 0; r < 4; ++r){
                int node = base + wrow*16 + quad*4 + r;
                if (node < NND)
                    z_out[(size_t)node*NH + f] = acc[tt][r] + bv;
            }
        }
    }
}

__device__ __forceinline__ void acc4(uint2 u, float& a0, float& a1, float& a2, float& a3){
    a0 += __uint_as_float(u.x << 16);
    a1 += __uint_as_float(u.x & 0xFFFF0000u);
    a2 += __uint_as_float(u.y << 16);
    a3 += __uint_as_float(u.y & 0xFFFF0000u);
}

// 64-lane xor-shuffle of a u64 (two 32-bit shuffles)
__device__ __forceinline__ u64 shflx64(u64 v, int m){
    int lo = __shfl_xor((int)(unsigned)v, m, 64);
    int hi = __shfl_xor((int)(unsigned)(v >> 32), m, 64);
    return ((u64)(unsigned)hi << 32) | (unsigned)lo;
}

// ====== head v6: 512 threads; 8-deep compact-key gather + hybrid shuffle-bitonic
//        top-30 + 8-deep winner-row re-gather + conv + fc1 + fc2 + log_softmax ======
#define PSTR 33   // pT leading stride: 33 floats kills the 16-way bank conflict
__global__ __launch_bounds__(512, 4) void head4_kernel(
    const ushort_t* __restrict__ yb, const ushort_t* __restrict__ ykey,
    const int* __restrict__ offs, const ushort_t* __restrict__ csr,
    const float* __restrict__ z, const int* __restrict__ starts,
    const float* __restrict__ wT, const float* __restrict__ cbf,
    const float* __restrict__ l1wf, const float* __restrict__ l1bf,
    const float* __restrict__ l2wf, const float* __restrict__ l2bf,
    float* __restrict__ outp)
{
    __shared__ u64  keysL[512];          // only used for the 3 cross-wave stages
    __shared__ int  sel[32];
    __shared__ float pT[64*PSTR];        // pT[ch][rank], rank 0..29 used
    __shared__ float part[8*832];
    __shared__ float cbuf[832];
    __shared__ float fbuf[NH];
    __shared__ float logitsS[NCLS];
    int g = blockIdx.x, tid = threadIdx.x;
    int s = starts[g], e = starts[g+1];
    int cnt = e - s; if (cnt > 256) cnt = 256; if (cnt < 0) cnt = 0;

    // ---- phase A: key from compact ykey (8-deep, strictly in csr order) ----
    u64 key = 0xFFFFFFFFFFFFFFFFull;
    if (tid < cnt){
        int node = s + tid;
        int o0 = offs[node], o1 = offs[node+1];
        float a = 0.f;
        int ee = o0;
        for (; ee + 7 < o1; ee += 8){
            float v0 = __uint_as_float((unsigned)ykey[csr[ee+0]] << 16);
            float v1 = __uint_as_float((unsigned)ykey[csr[ee+1]] << 16);
            float v2 = __uint_as_float((unsigned)ykey[csr[ee+2]] << 16);
            float v3 = __uint_as_float((unsigned)ykey[csr[ee+3]] << 16);
            float v4 = __uint_as_float((unsigned)ykey[csr[ee+4]] << 16);
            float v5 = __uint_as_float((unsigned)ykey[csr[ee+5]] << 16);
            float v6 = __uint_as_float((unsigned)ykey[csr[ee+6]] << 16);
            float v7 = __uint_as_float((unsigned)ykey[csr[ee+7]] << 16);
            a += v0; a += v1; a += v2; a += v3;
            a += v4; a += v5; a += v6; a += v7;
        }
        for (; ee + 3 < o1; ee += 4){
            float v0 = __uint_as_float((unsigned)ykey[csr[ee+0]] << 16);
            float v1 = __uint_as_float((unsigned)ykey[csr[ee+1]] << 16);
            float v2 = __uint_as_float((unsigned)ykey[csr[ee+2]] << 16);
            float v3 = __uint_as_float((unsigned)ykey[csr[ee+3]] << 16);
            a += v0; a += v1; a += v2; a += v3;
        }
        for (; ee < o1; ++ee)
            a += __uint_as_float((unsigned)ykey[csr[ee]] << 16);
        float dd = (float)(o1 - o0); dd = dd > 1.f ? dd : 1.f;
        float inv = 1.f / dd;
        float v = a*inv + z[(size_t)node*NH + 63];
        v = v > 0.f ? v : 0.f;
        unsigned u = __float_as_uint(v);
        unsigned m = (u & 0x80000000u) ? ~u : (u | 0x80000000u);
        unsigned d = ~m;                               // descending map
        key = ((u64)d << 32) | (unsigned)tid;
    }

    // ---- hybrid bitonic sort over 256 keys (threads 256..511 sort dummies in a
    //      disjoint partner group; j<64 stages are in-register shuffles) ----
    for (int k = 2; k <= 256; k <<= 1){
        for (int j = k >> 1; j > 0; j >>= 1){
            u64 other;
            if (j >= 64){
                keysL[tid] = key;
                __syncthreads();
                other = keysL[tid ^ j];
            } else {
                other = shflx64(key, j);
            }
            bool keepMin = (((tid & j) == 0) == ((tid & k) == 0));
            bool less = key < other;
            key = (keepMin == less) ? key : other;
            if (j >= 64) __syncthreads();
        }
    }
    if (tid < KP)
        sel[tid] = (((unsigned)(key >> 32)) == 0xFFFFFFFFu) ? -1 : (int)(key & 0xFFFFFFFFu);
    __syncthreads();

    // ---- phase B: full-row re-gather for the 30 winners -> pT (8-deep, in order) ----
    {
        int r = tid >> 4;
        int q = tid & 15;
        if (r < KP){
            float4 v = make_float4(0.f,0.f,0.f,0.f);
            int li = sel[r];
            if (li >= 0){
                int node = s + li;
                int o0 = offs[node], o1 = offs[node+1];
                float a0=0.f, a1=0.f, a2=0.f, a3=0.f;
                int ee = o0;
                for (; ee + 7 < o1; ee += 8){
                    int s0 = csr[ee],   s1 = csr[ee+1], s2 = csr[ee+2], s3 = csr[ee+3];
                    int s4 = csr[ee+4], s5 = csr[ee+5], s6 = csr[ee+6], s7 = csr[ee+7];
                    uint2 u0 = *(const uint2*)&yb[(size_t)s0*NH + q*4];
                    uint2 u1 = *(const uint2*)&yb[(size_t)s1*NH + q*4];
                    uint2 u2 = *(const uint2*)&yb[(size_t)s2*NH + q*4];
                    uint2 u3 = *(const uint2*)&yb[(size_t)s3*NH + q*4];
                    uint2 u4 = *(const uint2*)&yb[(size_t)s4*NH + q*4];
                    uint2 u5 = *(const uint2*)&yb[(size_t)s5*NH + q*4];
                    uint2 u6 = *(const uint2*)&yb[(size_t)s6*NH + q*4];
                    uint2 u7 = *(const uint2*)&yb[(size_t)s7*NH + q*4];
                    acc4(u0, a0,a1,a2,a3); acc4(u1, a0,a1,a2,a3);
                    acc4(u2, a0,a1,a2,a3); acc4(u3, a0,a1,a2,a3);
                    acc4(u4, a0,a1,a2,a3); acc4(u5, a0,a1,a2,a3);
                    acc4(u6, a0,a1,a2,a3); acc4(u7, a0,a1,a2,a3);
                }
                for (; ee + 3 < o1; ee += 4){
                    int s0 = csr[ee], s1 = csr[ee+1], s2 = csr[ee+2], s3 = csr[ee+3];
                    uint2 u0 = *(const uint2*)&yb[(size_t)s0*NH + q*4];
                    uint2 u1 = *(const uint2*)&yb[(size_t)s1*NH + q*4];
                    uint2 u2 = *(const uint2*)&yb[(size_t)s2*NH + q*4];
                    uint2 u3 = *(const uint2*)&yb[(size_t)s3*NH + q*4];
                    acc4(u0, a0,a1,a2,a3); acc4(u1, a0,a1,a2,a3);
                    acc4(u2, a0,a1,a2,a3); acc4(u3, a0,a1,a2,a3);
                }
                for (; ee < o1; ++ee){
                    uint2 u = *(const uint2*)&yb[(size_t)csr[ee]*NH + q*4];
                    acc4(u, a0,a1,a2,a3);
                }
                float dd = (float)(o1 - o0); dd = dd > 1.f ? dd : 1.f;
                float inv = 1.f / dd;
                float4 zz = *(const float4*)&z[(size_t)node*NH + q*4];
                v.x = a0*inv + zz.x; v.y = a1*inv + zz.y;
                v.z = a2*inv + zz.z; v.w = a3*inv + zz.w;
                v.x = v.x > 0.f ? v.x : 0.f;  v.y = v.y > 0.f ? v.y : 0.f;
                v.z = v.z > 0.f ? v.z : 0.f;  v.w = v.w > 0.f ? v.w : 0.f;
            }
            pT[(q*4+0)*PSTR + r] = v.x;
            pT[(q*4+1)*PSTR + r] = v.y;
            pT[(q*4+2)*PSTR + r] = v.z;
            pT[(q*4+3)*PSTR + r] = v.w;
        }
    }
    __syncthreads();

    // ---- conv1d: 512 threads = 32 o x 8 chg x 2 t-halves (13 positions each) ----
    {
        int o = tid & 31, th = (tid >> 5) & 1, chg = tid >> 6;   // chg 0..7
        int tbase = th*13;
        float acc[13];
        #pragma unroll
        for (int t = 0; t < 13; ++t) acc[t] = 0.f;
        for (int c8 = 0; c8 < 8; ++c8){
            int ch = chg*8 + c8;
            float p[17];
            #pragma unroll
            for (int i = 0; i < 17; ++i) p[i] = pT[ch*PSTR + tbase + i];  // broadcast reads
            const float* wrow = &wT[ch*160 + o];
            #pragma unroll
            for (int h = 0; h < 5; ++h){
                float wv = wrow[h*32];
                #pragma unroll
                for (int t = 0; t < 13; ++t) acc[t] += p[t+h]*wv;
            }
        }
        #pragma unroll
        for (int t = 0; t < 13; ++t) part[chg*832 + o*26 + tbase + t] = acc[t];
    }
    __syncthreads();

    for (int i = tid; i < 832; i += 512){
        int oo = i / 26;
        float a = cbf[oo];
        #pragma unroll
        for (int cg = 0; cg < 8; ++cg) a += part[cg*832 + i];
        cbuf[i] = a > 0.f ? a : 0.f;
    }
    __syncthreads();

    {   // fc1: 832 -> 64, 8 slices of 104
        int p8 = tid >> 6, j = tid & 63;
        float a = 0.f;
        int m0 = p8*104;
        #pragma unroll 4
        for (int m = m0; m < m0 + 104; ++m)
            a += cbuf[m] * l1wf[(size_t)m*NH + j];
        part[p8*NH + j] = a;
    }
    __syncthreads();
    if (tid < NH){
        float v = part[tid];
        #pragma unroll
        for (int p8 = 1; p8 < 8; ++p8) v += part[p8*NH + tid];
        v += l1bf[tid];
        fbuf[tid] = v > 0.f ? v : 0.f;
    }
    __syncthreads();
    if (tid < NCLS){
        float a = l2bf[tid];
        #pragma unroll
        for (int j = 0; j < NH; ++j) a += fbuf[j] * l2wf[j*NCLS + tid];
        logitsS[tid] = a;
    }
    __syncthreads();
    if (tid == 0){
        float m = logitsS[0];
        for (int c = 1; c < NCLS; ++c) m = fmaxf(m, logitsS[c]);
        float ssum = 0.f;
        for (int c = 0; c < NCLS; ++c) ssum += expf(logitsS[c]-m);
        float lse = m + logf(ssum);
        for (int c = 0; c < NCLS; ++c)
            outp[(size_t)g*NCLS + c] = logitsS[c] - lse;
    }
}

extern "C" void kernel_launch(void* const* d_in, const int* in_sizes, int n_in,
                              void* d_out, int out_size, void* d_ws, size_t ws_size,
                              hipStream_t stream) {
    const void* x    = d_in[0];
    const int*  ei   = (const int*)d_in[1];
    const int*  batch= (const int*)d_in[2];
    const void *W1l=d_in[3], *b1=d_in[4],  *W1r=d_in[5];
    const void *W2l=d_in[6], *b2=d_in[7],  *W2r=d_in[8];
    const void *W3l=d_in[9], *b3=d_in[10], *W3r=d_in[11];
    const void *convw=d_in[12], *convb=d_in[13];
    const void *l1w=d_in[14], *l1b=d_in[15];
    const void *l2w=d_in[16], *l2b=d_in[17];
    float* out = (float*)d_out;

    float* wsf = (float*)d_ws;
    ushort_t* yA = (ushort_t*)wsf;                        // NND*64 bf16
    float* zA  = wsf + (size_t)NND*NH/2;                  // NND*64 f32
    ushort_t* yB = (ushort_t*)(zA + (size_t)NND*NH);      // NND*64 bf16
    float* zB  = (float*)(yB + (size_t)NND*NH);           // NND*64 f32
    unsigned* bedges = (unsigned*)(zB + (size_t)NND*NH);  // NE uint ((dst<<16)|src)
    ushort_t* wB1 = (ushort_t*)(bedges + NE);             // 16384
    ushort_t* wB2 = wB1 + 16384;                          // 8192
    ushort_t* wB3 = wB2 + 8192;                           // 8192
    ushort_t* ykey = wB3 + 8192;                          // NND (compact y3[:,63])
    float* b1f  = (float*)(ykey + NND + 8);               // 64
    float* b2f  = b1f + 64;
    float* b3f  = b2f + 64;
    float* wT   = b3f + 64;                               // 10240
    float* cbf  = wT + 10240;                             // 32
    float* l1wf = cbf + 32;                               // 53248
    float* l1bf = l1wf + 53248;                           // 64
    float* l2wf = l1bf + 64;                              // 640
    float* l2bf = l2wf + 640;                             // 10 (+pad)
    int* starts = (int*)(l2bf + 16);                      // 513 (pad 520)
    int* bcnt   = starts + 520;                           // 196
    int* dctr   = bcnt + NBKT;                            // 1   (contiguous w/ bcnt)
    int* bbase  = dctr + 1;                               // 197 (pad 200)
    int* bcur   = bbase + 200;                            // 196 (pad 200)
    int* offs   = bcur + 200;                             // 50001 (pad +3)
    ushort_t* csr = (ushort_t*)(offs + NND + 4);          // NE u16

    // zero bcnt[196] + dctr (contiguous 197 ints)
    (void)hipMemsetAsync(bcnt, 0, (NBKT + 1)*sizeof(int), stream);

    // K1: count(+scan fold) || setup
    k1_kernel<<<NTILE + NSET, 256, 0, stream>>>(
        (const unsigned*)x, ei, batch, starts,
        W1l, W1r, b1, W2l, W2r, b2, W3l, W3r, b3,
        convw, convb, l1w, l1b, l2w, l2b,
        wB1, wB2, wB3, b1f, b2f, b3f,
        wT, cbf, l1wf, l1bf, l2wf, l2bf,
        bcnt, dctr, bbase, bcur, offs);

    // K2: layer-1 GEMM || bucket_scatter (packed uint bedges)
    k2_kernel<<<NG1 + NTILE, 256, 0, stream>>>(
        x, ei, wB1, b1f, yA, zA, bcur, bedges);

    // K3: per-bucket fine CSR finalize (196 blocks x 256)
    csr_finalize<<<NBKT, 256, 0, stream>>>(bedges, bbase, offs, csr);

    // K4/K5: fused gather+GEMM layers 2 and 3 (K5 also emits compact ykey)
    gather_mfma<<<NG1, 512, 0, stream>>>(yA, offs, csr, zA, wB2, b2f, yB, zB, nullptr);
    gather_mfma<<<NG1, 512, 0, stream>>>(yB, offs, csr, zB, wB3, b3f, yA, zA, ykey);

    // K6: fused final-gather + sort-pool + conv + MLP + log_softmax
    head4_kernel<<<NB, 512, 0, stream>>>(yA, ykey, offs, csr, zA, starts,
                                         wT, cbf, l1wf, l1bf, l2wf, l2bf, out);
}

// Round 7
// 211.573 us; speedup vs baseline: 1.0576x; 1.0576x over previous
//
#include <hip/hip_runtime.h>
#include <hip/hip_bf16.h>
#include <math.h>

#define NND 50000
#define NE 800000
#define NF 128
#define NH 64
#define NB 512
#define KP 30
#define NCLS 10
#define NBKT 196             // fine buckets of 256 dsts
#define BSH 8                // bucket shift (dst >> 8)
#define ECAP 6144            // fixed bucket capacity (mean 4082, +32 sigma)
#define NTILE 196            // edge tiles of 4096
#define NG1 782              // layer GEMM blocks (64 nodes each)
#define NSET 208             // setup blocks (208*256 = 53248)

typedef __hip_bfloat16 bf16;
typedef unsigned long long u64;
typedef unsigned short ushort_t;
typedef __attribute__((ext_vector_type(8))) short bf16x8;   // 8 bf16 (4 VGPRs)
typedef __attribute__((ext_vector_type(4))) float f32x4;

__device__ __forceinline__ float ldF(const void* p, size_t i, int isbf){
    return isbf ? __bfloat162float(((const bf16*)p)[i]) : ((const float*)p)[i];
}

// fp32 -> bf16 bits, round-to-nearest-even (matches HW/numpy)
__device__ __forceinline__ ushort_t f2bf(float v){
    unsigned u = __float_as_uint(v);
    unsigned r = u + 0x7FFFu + ((u >> 16) & 1u);
    return (ushort_t)(r >> 16);
}

// ---- wave-uniform dtype detection (no LDS, no barriers; all lanes must be active) ----
__device__ __forceinline__ int floatsAreBf16(const unsigned* __restrict__ xw, int tid){
    unsigned w = xw[tid & 63];
    int ex = (int)((w >> 7) & 0xFF);
    u64 m = __ballot(ex >= 100 && ex <= 140);   // low-half bf16 exponent sanity
    return __popcll(m) >= 32;
}
__device__ __forceinline__ int intsAreI64(const int* __restrict__ ew, int tid){
    u64 m = __ballot(ew[2*(tid & 63) + 1] == 0); // LE int64 -> odd words zero
    return __popcll(m) >= 48;
}

// ========== K1: single-pass bucket SCATTER (+last-block scan fold) || setup ==========
// bedges entry: (dst<<16) | src, at fixed-stride bucket regions b*ECAP + offset.
// Last scatter block (dctr) scans bcur -> bbase. bedges is only read by the NEXT
// dispatch (kernel boundary = coherence barrier); the fold reads only atomics.
__global__ __launch_bounds__(256) void k1_kernel(
    const unsigned* __restrict__ xw, const int* __restrict__ ei,
    const int* __restrict__ batch, int* __restrict__ starts,
    const void* W1l, const void* W1r, const void* b1,
    const void* W2l, const void* W2r, const void* b2,
    const void* W3l, const void* W3r, const void* b3,
    const void* convw, const void* convb,
    const void* l1w, const void* l1b, const void* l2w, const void* l2b,
    ushort_t* __restrict__ wB1, ushort_t* __restrict__ wB2, ushort_t* __restrict__ wB3,
    float* __restrict__ b1f, float* __restrict__ b2f, float* __restrict__ b3f,
    float* __restrict__ wT, float* __restrict__ cbf,
    float* __restrict__ l1wf, float* __restrict__ l1bf,
    float* __restrict__ l2wf, float* __restrict__ l2bf,
    unsigned* __restrict__ bedges, int* __restrict__ bcur, int* __restrict__ dctr,
    int* __restrict__ bbase, int* __restrict__ offs)
{
    int tid = threadIdx.x;
    if (blockIdx.x < NTILE){
        // ---- single-pass bucket scatter (static-index regs; LDS hist batches atomics) ----
        __shared__ int lh[NBKT];
        __shared__ int lcur[NBKT];
        __shared__ int sc[NBKT];
        __shared__ int lastFlag;
        int i64 = intsAreI64(ei, tid);
        if (tid < NBKT) lh[tid] = 0;
        __syncthreads();
        int t0 = blockIdx.x*4096;
        int myd[16], mys[16];
        if (i64){
            #pragma unroll
            for (int k = 0; k < 8; ++k){
                int e = t0 + k*512 + 2*tid;
                int d0 = -1, d1 = -1, s0 = 0, s1 = 0;
                if (e < NE){
                    int4 sp = *(const int4*)&ei[2*e];
                    int4 dp = *(const int4*)&ei[2*NE + 2*e];
                    d0 = dp.x; s0 = sp.x; d1 = dp.z; s1 = sp.z;
                    atomicAdd(&lh[d0 >> BSH], 1);
                    atomicAdd(&lh[d1 >> BSH], 1);
                }
                myd[2*k]   = d0; mys[2*k]   = s0;
                myd[2*k+1] = d1; mys[2*k+1] = s1;
            }
        } else {
            #pragma unroll
            for (int k = 0; k < 16; ++k){
                int e = t0 + k*256 + tid;
                int d = -1, s_ = 0;
                if (e < NE){
                    d = ei[NE + e]; s_ = ei[e];
                    atomicAdd(&lh[d >> BSH], 1);
                }
                myd[k] = d; mys[k] = s_;
            }
        }
        __syncthreads();
        if (tid < NBKT)
            lcur[tid] = tid*ECAP + (lh[tid] ? atomicAdd(&bcur[tid], lh[tid]) : 0);
        __syncthreads();
        #pragma unroll
        for (int k = 0; k < 16; ++k){
            if (myd[k] >= 0){
                int b = myd[k] >> BSH;
                int p = atomicAdd(&lcur[b], 1);
                bedges[p] = ((unsigned)myd[k] << 16) | (unsigned)mys[k];
            }
        }
        // ---- fold: last scatter block scans bcur -> bbase ----
        __syncthreads();
        if (tid == 0){
            __threadfence();
            int old = atomicAdd(dctr, 1);
            lastFlag = (old == NTILE-1) ? 1 : 0;
        }
        __syncthreads();
        if (lastFlag){
            if (tid < NBKT) sc[tid] = atomicAdd(&bcur[tid], 0);   // atomic read
            __syncthreads();
            if (tid == 0){
                int acc = 0;
                for (int b = 0; b < NBKT; ++b){
                    bbase[b] = acc; acc += sc[b];
                }
                bbase[NBKT] = acc;
                offs[NND] = NE;
            }
        }
    } else {
        // ---- setup: starts + weight preconvert + MFMA B-frag swizzle ----
        int wbf = floatsAreBf16(xw, tid);
        int i64 = intsAreI64(ei, tid);
        int i = (blockIdx.x - NTILE)*256 + tid;
        if (i < NND){
            int b  = i64 ? batch[2*i] : batch[i];
            int pb = (i == 0) ? -1 : (i64 ? batch[2*(i-1)] : batch[i-1]);
            for (int g = pb+1; g <= b; ++g) starts[g] = i;
            if (i == NND-1) for (int g = b+1; g <= NB; ++g) starts[g] = NND;
        }
        // B-frag swizzle: [c][t][lane][j]; k=c*32+(lane>>4)*8+j, n=t*16+(lane&15)
        {
            int j = i & 7, lane = (i >> 3) & 63, t = (i >> 9) & 7, c = i >> 12;
            int k = c*32 + (lane >> 4)*8 + j;
            int n = t*16 + (lane & 15);
            if (i < 16384){
                float v = (n < 64) ? ldF(W1l, (size_t)k*NH + n, wbf)
                                   : ldF(W1r, (size_t)k*NH + (n-64), wbf);
                wB1[i] = f2bf(v);
            }
            if (i < 8192){
                float v2 = (n < 64) ? ldF(W2l, (size_t)k*NH + n, wbf)
                                    : ldF(W2r, (size_t)k*NH + (n-64), wbf);
                float v3 = (n < 64) ? ldF(W3l, (size_t)k*NH + n, wbf)
                                    : ldF(W3r, (size_t)k*NH + (n-64), wbf);
                wB2[i] = f2bf(v2);
                wB3[i] = f2bf(v3);
            }
        }
        if (i < 64){
            b1f[i] = ldF(b1, i, wbf);
            b2f[i] = ldF(b2, i, wbf);
            b3f[i] = ldF(b3, i, wbf);
            l1bf[i] = ldF(l1b, i, wbf);
        }
        if (i < 10240){
            int o = i / 320, rem = i - o*320, ch = rem/5, h = rem - ch*5;
            wT[ch*160 + h*32 + o] = ldF(convw, i, wbf);   // wT[ch][h][o]
        }
        if (i < 53248) l1wf[i] = ldF(l1w, i, wbf);
        if (i < 640)   l2wf[i] = ldF(l2w, i, wbf);
        if (i < 32)    cbf[i]  = ldF(convb, i, wbf);
        if (i < 10)    l2bf[i] = ldF(l2b, i, wbf);
    }
}

// ========== K2: layer-1 MFMA GEMM || per-bucket CSR finalize (both depend only on K1) ==========
__global__ __launch_bounds__(256) void k2_kernel(
    const void* __restrict__ x,
    const ushort_t* __restrict__ wB1, const float* __restrict__ b1f,
    ushort_t* __restrict__ ybf, float* __restrict__ z,
    const unsigned* __restrict__ bedges, const int* __restrict__ bbase,
    const int* __restrict__ bcur, int* __restrict__ offs,
    ushort_t* __restrict__ csr)
{
    int tid = threadIdx.x;
    if (blockIdx.x < NG1){
        // ---- L1 GEMM: [y|z] = x @ [W1l|W1r] + [0|b1], K=128 ----
        constexpr int K = NF, KC = K/32, RS = K + 8;
        __shared__ ushort_t hA[64*RS];
        int isbf = floatsAreBf16((const unsigned*)x, tid);
        int base = blockIdx.x * 64;
        // vectorized A-staging: 8 elements per iteration per thread
        if (isbf){
            for (int j = tid; j < 64*K/8; j += 256){
                int r = j >> 4, c8 = (j & 15)*8;
                int node = base + r;
                uint4 v = make_uint4(0u,0u,0u,0u);
                if (node < NND)
                    v = *(const uint4*)((const ushort_t*)x + (size_t)node*K + c8);
                *(uint4*)&hA[r*RS + c8] = v;     // bf16 passthrough (f2bf round-trip exact)
            }
        } else {
            for (int j = tid; j < 64*K/8; j += 256){
                int r = j >> 4, c8 = (j & 15)*8;
                int node = base + r;
                uint4 pk = make_uint4(0u,0u,0u,0u);
                if (node < NND){
                    const float4* xp = (const float4*)((const float*)x + (size_t)node*K + c8);
                    float4 a = xp[0], b = xp[1];
                    pk.x = (unsigned)f2bf(a.x) | ((unsigned)f2bf(a.y) << 16);
                    pk.y = (unsigned)f2bf(a.z) | ((unsigned)f2bf(a.w) << 16);
                    pk.z = (unsigned)f2bf(b.x) | ((unsigned)f2bf(b.y) << 16);
                    pk.w = (unsigned)f2bf(b.z) | ((unsigned)f2bf(b.w) << 16);
                }
                *(uint4*)&hA[r*RS + c8] = pk;
            }
        }
        __syncthreads();
        int lane = tid & 63, w = tid >> 6;
        int n16 = lane & 15, quad = lane >> 4;
        f32x4 acc[8];
        #pragma unroll
        for (int t = 0; t < 8; ++t) acc[t] = (f32x4){0.f,0.f,0.f,0.f};
        const bf16x8* bp = (const bf16x8*)wB1;
        #pragma unroll
        for (int c = 0; c < KC; ++c){
            bf16x8 a = *(const bf16x8*)&hA[(w*16 + n16)*RS + c*32 + quad*8];
            #pragma unroll
            for (int t = 0; t < 8; ++t){
                bf16x8 b = bp[(c*8 + t)*64 + lane];
                acc[t] = __builtin_amdgcn_mfma_f32_16x16x32_bf16(a, b, acc[t], 0, 0, 0);
            }
        }
        #pragma unroll
        for (int t = 0; t < 8; ++t){
            int f = (t & 3)*16 + n16;
            float bv = (t >= 4) ? b1f[f] : 0.f;
            #pragma unroll
            for (int r = 0; r < 4; ++r){
                int node = base + w*16 + quad*4 + r;
                if (node < NND){
                    if (t < 4) ybf[(size_t)node*NH + f] = f2bf(acc[t][r]);
                    else       z[(size_t)node*NH + f] = acc[t][r] + bv;
                }
            }
        }
    } else {
        // ---- per-bucket fine CSR finalize (depends only on K1 outputs) ----
        __shared__ int hist[256];
        int b = blockIdx.x - NG1;
        int dst0 = b << BSH;
        int nd = NND - dst0; if (nd > 256) nd = 256; if (nd < 0) nd = 0;
        int e0 = bbase[b];
        int cnt = bcur[b];                         // final per-bucket count
        const unsigned* be = bedges + (size_t)b*ECAP;
        hist[tid] = 0;
        __syncthreads();
        for (int i = tid; i < cnt; i += 256)
            atomicAdd(&hist[(int)(be[i] >> 16) - dst0], 1);
        __syncthreads();
        int own = hist[tid];
        for (int st = 1; st < 256; st <<= 1){
            int v = (tid >= st) ? hist[tid-st] : 0;
            __syncthreads();
            hist[tid] += v;
            __syncthreads();
        }
        int excl = hist[tid] - own;
        if (tid < nd) offs[dst0 + tid] = e0 + excl;
        __syncthreads();
        hist[tid] = excl;
        __syncthreads();
        for (int i = tid; i < cnt; i += 256){
            unsigned ed = be[i];
            int p = atomicAdd(&hist[(int)(ed >> 16) - dst0], 1);
            csr[e0 + p] = (ushort_t)(ed & 0xFFFFu);
        }
    }
}

__device__ __forceinline__ void addbf8(uint4 u, float* a){
    a[0] += __uint_as_float(u.x << 16);
    a[1] += __uint_as_float(u.x & 0xFFFF0000u);
    a[2] += __uint_as_float(u.y << 16);
    a[3] += __uint_as_float(u.y & 0xFFFF0000u);
    a[4] += __uint_as_float(u.z << 16);
    a[5] += __uint_as_float(u.z & 0xFFFF0000u);
    a[6] += __uint_as_float(u.w << 16);
    a[7] += __uint_as_float(u.w & 0xFFFF0000u);
}

// ------ FUSED: h = relu(mean_csr(y)+z) -> LDS A-tile -> MFMA [y'|z'] (layers 2,3) ----
// 512 threads: phase A = 8 threads/node (1 uint4/edge); MFMA split across 8 waves
// (waves 0-3: t=0..3 -> y-out; waves 4-7: t=4..7 -> z-out).
__global__ __launch_bounds__(512) void gather_mfma(
    const ushort_t* __restrict__ yb, const int* __restrict__ offs,
    const ushort_t* __restrict__ csr, const float* __restrict__ z,
    const ushort_t* __restrict__ wB, const float* __restrict__ bfp,
    ushort_t* __restrict__ ybf_out, float* __restrict__ z_out,
    ushort_t* __restrict__ ykey_out)
{
    constexpr int K = NH;
    constexpr int KC = K/32;
    constexpr int RS = K + 8;
    __shared__ ushort_t hA[64*RS];
    int tid = threadIdx.x;
    int base = blockIdx.x * 64;

    {   // phase A: gather+finalize 64 nodes into hA, 8 threads per node
        int nl = tid >> 3, q = tid & 7;      // q: 8-feature column group
        int node = base + nl;
        float acc[8];
        #pragma unroll
        for (int i = 0; i < 8; ++i) acc[i] = 0.f;
        ushort_t row[8];
        if (node < NND){
            int o0 = offs[node], o1 = offs[node+1];
            int e = o0;
            for (; e + 3 < o1; e += 4){
                int s0 = csr[e], s1 = csr[e+1], s2 = csr[e+2], s3 = csr[e+3];
                uint4 a0 = *(const uint4*)&yb[(size_t)s0*NH + q*8];
                uint4 b0 = *(const uint4*)&yb[(size_t)s1*NH + q*8];
                uint4 c0 = *(const uint4*)&yb[(size_t)s2*NH + q*8];
                uint4 d0 = *(const uint4*)&yb[(size_t)s3*NH + q*8];
                addbf8(a0, acc); addbf8(b0, acc); addbf8(c0, acc); addbf8(d0, acc);
            }
            for (; e < o1; ++e){
                uint4 a0 = *(const uint4*)&yb[(size_t)csr[e]*NH + q*8];
                addbf8(a0, acc);
            }
            float dd = (float)(o1 - o0); dd = dd > 1.f ? dd : 1.f;
            float inv = 1.f / dd;
            const float4* zp = (const float4*)&z[(size_t)node*NH + q*8];
            #pragma unroll
            for (int i4 = 0; i4 < 2; ++i4){
                float4 zz = zp[i4];
                float v0 = acc[i4*4+0]*inv + zz.x;
                float v1 = acc[i4*4+1]*inv + zz.y;
                float v2 = acc[i4*4+2]*inv + zz.z;
                float v3 = acc[i4*4+3]*inv + zz.w;
                row[i4*4+0] = f2bf(v0 > 0.f ? v0 : 0.f);
                row[i4*4+1] = f2bf(v1 > 0.f ? v1 : 0.f);
                row[i4*4+2] = f2bf(v2 > 0.f ? v2 : 0.f);
                row[i4*4+3] = f2bf(v3 > 0.f ? v3 : 0.f);
            }
        } else {
            #pragma unroll
            for (int i = 0; i < 8; ++i) row[i] = 0;
        }
        unsigned pk[4];
        #pragma unroll
        for (int i = 0; i < 4; ++i)
            pk[i] = (unsigned)row[2*i] | ((unsigned)row[2*i+1] << 16);
        *(uint4*)&hA[nl*RS + q*8] = make_uint4(pk[0],pk[1],pk[2],pk[3]);
    }
    __syncthreads();

    int lane = tid & 63, w8 = tid >> 6;
    int wrow = w8 & 3;                 // row-group 0..3 (rows wrow*16..+15)
    int thalf = (w8 >> 2) << 2;        // 0: y-half, 4: z-half
    int n16 = lane & 15, quad = lane >> 4;
    f32x4 acc[4];
    #pragma unroll
    for (int t = 0; t < 4; ++t) acc[t] = (f32x4){0.f,0.f,0.f,0.f};
    const bf16x8* bp = (const bf16x8*)wB;
    #pragma unroll
    for (int c = 0; c < KC; ++c){
        bf16x8 a = *(const bf16x8*)&hA[(wrow*16 + n16)*RS + c*32 + quad*8];
        #pragma unroll
        for (int tt = 0; tt < 4; ++tt){
            bf16x8 b = bp[(c*8 + thalf + tt)*64 + lane];
            acc[tt] = __builtin_amdgcn_mfma_f32_16x16x32_bf16(a, b, acc[tt], 0, 0, 0);
        }
    }
    if (thalf == 0){
        #pragma unroll
        for (int tt = 0; tt < 4; ++tt){
            int f = tt*16 + n16;
            #pragma unroll
            for (int r = 0; r < 4; ++r){
                int node = base + wrow*16 + quad*4 + r;
                if (node < NND){
                    ushort_t yv = f2bf(acc[tt][r]);
                    ybf_out[(size_t)node*NH + f] = yv;
                    if (ykey_out != nullptr && tt == 3 && n16 == 15)
                        ykey_out[node] = yv;          // compact y'[:,63] for sort keys
                }
            }
        }
    } else {
        #pragma unroll
        for (int tt = 0; tt < 4; ++tt){
            int f = tt*16 + n16;
            float bv = bfp[f];
            #pragma unroll
            for (int r = 0; r < 4; ++r){
                int node = base + wrow*16 + quad*4 + r;
                if (node < NND)
                    z_out[(size_t)node*NH + f] = acc[tt][r] + bv;
            }
        }
    }
}

__device__ __forceinline__ void acc4(uint2 u, float& a0, float& a1, float& a2, float& a3){
    a0 += __uint_as_float(u.x << 16);
    a1 += __uint_as_float(u.x & 0xFFFF0000u);
    a2 += __uint_as_float(u.y << 16);
    a3 += __uint_as_float(u.y & 0xFFFF0000u);
}

// 64-lane xor-shuffle of a u64 (two 32-bit shuffles)
__device__ __forceinline__ u64 shflx64(u64 v, int m){
    int lo = __shfl_xor((int)(unsigned)v, m, 64);
    int hi = __shfl_xor((int)(unsigned)(v >> 32), m, 64);
    return ((u64)(unsigned)hi << 32) | (unsigned)lo;
}

// ====== head v5: 512 threads; compact-key gather + HYBRID shuffle-bitonic top-30
//        (6 barriers) + winner-row re-gather (1 pass) + conv + fc1 + fc2 + log_softmax ======
#define PSTR 33   // pT leading stride: 33 floats kills the 16-way bank conflict
__global__ __launch_bounds__(512, 4) void head4_kernel(
    const ushort_t* __restrict__ yb, const ushort_t* __restrict__ ykey,
    const int* __restrict__ offs, const ushort_t* __restrict__ csr,
    const float* __restrict__ z, const int* __restrict__ starts,
    const float* __restrict__ wT, const float* __restrict__ cbf,
    const float* __restrict__ l1wf, const float* __restrict__ l1bf,
    const float* __restrict__ l2wf, const float* __restrict__ l2bf,
    float* __restrict__ outp)
{
    __shared__ u64  keysL[512];          // only used for the 3 cross-wave stages
    __shared__ int  sel[32];
    __shared__ float pT[64*PSTR];        // pT[ch][rank], rank 0..29 used
    __shared__ float part[8*832];
    __shared__ float cbuf[832];
    __shared__ float fbuf[NH];
    __shared__ float logitsS[NCLS];
    int g = blockIdx.x, tid = threadIdx.x;
    int s = starts[g], e = starts[g+1];
    int cnt = e - s; if (cnt > 256) cnt = 256; if (cnt < 0) cnt = 0;

    // ---- phase A: key from compact ykey (L2-resident 100KB; same order as gather) ----
    u64 key = 0xFFFFFFFFFFFFFFFFull;
    if (tid < cnt){
        int node = s + tid;
        int o0 = offs[node], o1 = offs[node+1];
        float a = 0.f;
        int ee = o0;
        for (; ee + 3 < o1; ee += 4){
            float v0 = __uint_as_float((unsigned)ykey[csr[ee+0]] << 16);
            float v1 = __uint_as_float((unsigned)ykey[csr[ee+1]] << 16);
            float v2 = __uint_as_float((unsigned)ykey[csr[ee+2]] << 16);
            float v3 = __uint_as_float((unsigned)ykey[csr[ee+3]] << 16);
            a += v0; a += v1; a += v2; a += v3;       // same order as full gather
        }
        for (; ee < o1; ++ee)
            a += __uint_as_float((unsigned)ykey[csr[ee]] << 16);
        float dd = (float)(o1 - o0); dd = dd > 1.f ? dd : 1.f;
        float inv = 1.f / dd;
        float v = a*inv + z[(size_t)node*NH + 63];
        v = v > 0.f ? v : 0.f;
        unsigned u = __float_as_uint(v);
        unsigned m = (u & 0x80000000u) ? ~u : (u | 0x80000000u);
        unsigned d = ~m;                               // descending map
        key = ((u64)d << 32) | (unsigned)tid;
    }

    // ---- hybrid bitonic sort over 256 keys (threads 256..511 sort dummies in a
    //      disjoint partner group; j<64 stages are in-register shuffles) ----
    for (int k = 2; k <= 256; k <<= 1){
        for (int j = k >> 1; j > 0; j >>= 1){
            u64 other;
            if (j >= 64){
                keysL[tid] = key;
                __syncthreads();
                other = keysL[tid ^ j];
            } else {
                other = shflx64(key, j);
            }
            bool keepMin = (((tid & j) == 0) == ((tid & k) == 0));
            bool less = key < other;
            key = (keepMin == less) ? key : other;
            if (j >= 64) __syncthreads();
        }
    }
    if (tid < KP)
        sel[tid] = (((unsigned)(key >> 32)) == 0xFFFFFFFFu) ? -1 : (int)(key & 0xFFFFFFFFu);
    __syncthreads();

    // ---- phase B: full-row re-gather for the 30 winners -> pT, single pass ----
    {
        int r = tid >> 4;
        int q = tid & 15;
        if (r < KP){
            float4 v = make_float4(0.f,0.f,0.f,0.f);
            int li = sel[r];
            if (li >= 0){
                int node = s + li;
                int o0 = offs[node], o1 = offs[node+1];
                float a0=0.f, a1=0.f, a2=0.f, a3=0.f;
                int ee = o0;
                for (; ee + 3 < o1; ee += 4){
                    int s0 = csr[ee], s1 = csr[ee+1], s2 = csr[ee+2], s3 = csr[ee+3];
                    uint2 u0 = *(const uint2*)&yb[(size_t)s0*NH + q*4];
                    uint2 u1 = *(const uint2*)&yb[(size_t)s1*NH + q*4];
                    uint2 u2 = *(const uint2*)&yb[(size_t)s2*NH + q*4];
                    uint2 u3 = *(const uint2*)&yb[(size_t)s3*NH + q*4];
                    acc4(u0, a0,a1,a2,a3); acc4(u1, a0,a1,a2,a3);
                    acc4(u2, a0,a1,a2,a3); acc4(u3, a0,a1,a2,a3);
                }
                for (; ee < o1; ++ee){
                    uint2 u = *(const uint2*)&yb[(size_t)csr[ee]*NH + q*4];
                    acc4(u, a0,a1,a2,a3);
                }
                float dd = (float)(o1 - o0); dd = dd > 1.f ? dd : 1.f;
                float inv = 1.f / dd;
                float4 zz = *(const float4*)&z[(size_t)node*NH + q*4];
                v.x = a0*inv + zz.x; v.y = a1*inv + zz.y;
                v.z = a2*inv + zz.z; v.w = a3*inv + zz.w;
                v.x = v.x > 0.f ? v.x : 0.f;  v.y = v.y > 0.f ? v.y : 0.f;
                v.z = v.z > 0.f ? v.z : 0.f;  v.w = v.w > 0.f ? v.w : 0.f;
            }
            pT[(q*4+0)*PSTR + r] = v.x;
            pT[(q*4+1)*PSTR + r] = v.y;
            pT[(q*4+2)*PSTR + r] = v.z;
            pT[(q*4+3)*PSTR + r] = v.w;
        }
    }
    __syncthreads();

    // ---- conv1d: 512 threads = 32 o x 8 chg x 2 t-halves (13 positions each) ----
    {
        int o = tid & 31, th = (tid >> 5) & 1, chg = tid >> 6;   // chg 0..7
        int tbase = th*13;
        float acc[13];
        #pragma unroll
        for (int t = 0; t < 13; ++t) acc[t] = 0.f;
        for (int c8 = 0; c8 < 8; ++c8){
            int ch = chg*8 + c8;
            float p[17];
            #pragma unroll
            for (int i = 0; i < 17; ++i) p[i] = pT[ch*PSTR + tbase + i];  // broadcast reads
            const float* wrow = &wT[ch*160 + o];
            #pragma unroll
            for (int h = 0; h < 5; ++h){
                float wv = wrow[h*32];
                #pragma unroll
                for (int t = 0; t < 13; ++t) acc[t] += p[t+h]*wv;
            }
        }
        #pragma unroll
        for (int t = 0; t < 13; ++t) part[chg*832 + o*26 + tbase + t] = acc[t];
    }
    __syncthreads();

    for (int i = tid; i < 832; i += 512){
        int oo = i / 26;
        float a = cbf[oo];
        #pragma unroll
        for (int cg = 0; cg < 8; ++cg) a += part[cg*832 + i];
        cbuf[i] = a > 0.f ? a : 0.f;
    }
    __syncthreads();

    {   // fc1: 832 -> 64, 8 slices of 104
        int p8 = tid >> 6, j = tid & 63;
        float a = 0.f;
        int m0 = p8*104;
        #pragma unroll 4
        for (int m = m0; m < m0 + 104; ++m)
            a += cbuf[m] * l1wf[(size_t)m*NH + j];
        part[p8*NH + j] = a;
    }
    __syncthreads();
    if (tid < NH){
        float v = part[tid];
        #pragma unroll
        for (int p8 = 1; p8 < 8; ++p8) v += part[p8*NH + tid];
        v += l1bf[tid];
        fbuf[tid] = v > 0.f ? v : 0.f;
    }
    __syncthreads();
    if (tid < NCLS){
        float a = l2bf[tid];
        #pragma unroll
        for (int j = 0; j < NH; ++j) a += fbuf[j] * l2wf[j*NCLS + tid];
        logitsS[tid] = a;
    }
    __syncthreads();
    if (tid == 0){
        float m = logitsS[0];
        for (int c = 1; c < NCLS; ++c) m = fmaxf(m, logitsS[c]);
        float ssum = 0.f;
        for (int c = 0; c < NCLS; ++c) ssum += expf(logitsS[c]-m);
        float lse = m + logf(ssum);
        for (int c = 0; c < NCLS; ++c)
            outp[(size_t)g*NCLS + c] = logitsS[c] - lse;
    }
}

extern "C" void kernel_launch(void* const* d_in, const int* in_sizes, int n_in,
                              void* d_out, int out_size, void* d_ws, size_t ws_size,
                              hipStream_t stream) {
    const void* x    = d_in[0];
    const int*  ei   = (const int*)d_in[1];
    const int*  batch= (const int*)d_in[2];
    const void *W1l=d_in[3], *b1=d_in[4],  *W1r=d_in[5];
    const void *W2l=d_in[6], *b2=d_in[7],  *W2r=d_in[8];
    const void *W3l=d_in[9], *b3=d_in[10], *W3r=d_in[11];
    const void *convw=d_in[12], *convb=d_in[13];
    const void *l1w=d_in[14], *l1b=d_in[15];
    const void *l2w=d_in[16], *l2b=d_in[17];
    float* out = (float*)d_out;

    float* wsf = (float*)d_ws;
    ushort_t* yA = (ushort_t*)wsf;                        // NND*64 bf16
    float* zA  = wsf + (size_t)NND*NH/2;                  // NND*64 f32
    ushort_t* yB = (ushort_t*)(zA + (size_t)NND*NH);      // NND*64 bf16
    float* zB  = (float*)(yB + (size_t)NND*NH);           // NND*64 f32
    unsigned* bedges = (unsigned*)(zB + (size_t)NND*NH);  // NBKT*ECAP uints ((dst<<16)|src)
    ushort_t* wB1 = (ushort_t*)(bedges + (size_t)NBKT*ECAP); // 16384
    ushort_t* wB2 = wB1 + 16384;                          // 8192
    ushort_t* wB3 = wB2 + 8192;                           // 8192
    ushort_t* ykey = wB3 + 8192;                          // NND (compact y3[:,63])
    float* b1f  = (float*)(ykey + NND + 8);               // 64
    float* b2f  = b1f + 64;
    float* b3f  = b2f + 64;
    float* wT   = b3f + 64;                               // 10240
    float* cbf  = wT + 10240;                             // 32
    float* l1wf = cbf + 32;                               // 53248
    float* l1bf = l1wf + 53248;                           // 64
    float* l2wf = l1bf + 64;                              // 640
    float* l2bf = l2wf + 640;                             // 10 (+pad)
    int* starts = (int*)(l2bf + 16);                      // 513 (pad 520)
    int* bcur   = starts + 520;                           // 196
    int* dctr   = bcur + NBKT;                            // 1   (contiguous: one memset)
    int* bbase  = dctr + 1;                               // 197 (pad 200)
    int* offs   = bbase + 200;                            // 50001 (pad +4)
    ushort_t* csr = (ushort_t*)(offs + NND + 4);          // NE u16

    // zero bcur[196] + dctr (contiguous 197 ints)
    (void)hipMemsetAsync(bcur, 0, (NBKT + 1)*sizeof(int), stream);

    // K1: single-pass scatter (+scan fold) || setup
    k1_kernel<<<NTILE + NSET, 256, 0, stream>>>(
        (const unsigned*)x, ei, batch, starts,
        W1l, W1r, b1, W2l, W2r, b2, W3l, W3r, b3,
        convw, convb, l1w, l1b, l2w, l2b,
        wB1, wB2, wB3, b1f, b2f, b3f,
        wT, cbf, l1wf, l1bf, l2wf, l2bf,
        bedges, bcur, dctr, bbase, offs);

    // K2: layer-1 GEMM || per-bucket CSR finalize (overlapped)
    k2_kernel<<<NG1 + NBKT, 256, 0, stream>>>(
        x, wB1, b1f, yA, zA, bedges, bbase, bcur, offs, csr);

    // K3/K4: fused gather+GEMM layers 2 and 3 (K4 also emits compact ykey)
    gather_mfma<<<NG1, 512, 0, stream>>>(yA, offs, csr, zA, wB2, b2f, yB, zB, nullptr);
    gather_mfma<<<NG1, 512, 0, stream>>>(yB, offs, csr, zB, wB3, b3f, yA, zA, ykey);

    // K5: fused final-gather + sort-pool + conv + MLP + log_softmax
    head4_kernel<<<NB, 512, 0, stream>>>(yA, ykey, offs, csr, zA, starts,
                                         wT, cbf, l1wf, l1bf, l2wf, l2bf, out);
}